// Round 5
// baseline (347.891 us; speedup 1.0000x reference)
//
#include <hip/hip_runtime.h>

// TransformerBlock: B=8,S=196,D=768,H=12,HD=64,E=8,FF=3072. T = B*S = 1568 tokens.
//
// Exact simplifications:
//  - attention: k,v broadcast across heads -> softmax uniform -> attn_out = tile(v).
//    Wq/bq/Wk/bk/RoPE are dead code.
//  - MoE top-1 = argmax of gating logits (softmax monotone).
//
// R4:
//  - k_wt: W1/W2 fp32 -> bf16 TRANSPOSED ([n][k], K-contiguous) once per call.
//    GEMM B-staging becomes wide bf16x8 loads (was 16 scalar strided dwords).
//  - gemm2: split-K x4 partials to workspace (NO atomics - R1..R3 plateaued at
//    ~100G atomicAdd/s across 3 configs), k_reduce folds partials into out.
//  - BK=64, NK=12 per K-chain; planner kernel removed (decode y + cheap drain).

typedef unsigned short u16;
typedef short bf16x8_t __attribute__((ext_vector_type(8)));
typedef short bf16x4_t __attribute__((ext_vector_type(4)));
typedef float f32x4_t  __attribute__((ext_vector_type(4)));

#define T_TOK 1568
#define DM 768
#define HD 64
#define FF 3072
#define NE 8
#define MT_MAX 13          // max m-tiles per expert at BM=128 (1568/128 -> 13)

// workspace layout (64B-aligned), total ~102 MB
#define OFF_CNT   0
#define OFF_BUCK  64
#define OFF_H2    50304
#define OFF_HMID  2458752
#define OFF_W1T   12092544
#define OFF_W2T   49841280
#define OFF_PART  87590016

__device__ __forceinline__ float bf2f(u16 h) {
    unsigned u = ((unsigned)h) << 16;
    return __builtin_bit_cast(float, u);
}
__device__ __forceinline__ u16 f2bf(float f) {  // round-to-nearest-even
    unsigned u = __builtin_bit_cast(unsigned, f);
    unsigned r = (u + 0x7FFFu + ((u >> 16) & 1u)) >> 16;
    return (u16)r;
}
__device__ __forceinline__ float gelu_f(float x) {
    return 0.5f * x * (1.0f + erff(x * 0.70710678118654752440f));
}

// ---- K0: transpose+convert weights: W1 [D][FF] -> W1t bf16 [FF][D];
//          W2 [FF][D] -> W2t bf16 [D][FF].  64x64 tiles via LDS. ----
__global__ __launch_bounds__(256) void k_wt(const float* __restrict__ W1,
                                            const float* __restrict__ W2,
                                            u16* __restrict__ W1t,
                                            u16* __restrict__ W2t) {
    __shared__ __align__(16) u16 Ls[64 * 68];
    int z = blockIdx.z;
    const float* src;
    u16* dst;
    int K, N, k0, n0;
    if (z < 8) {  // W1 expert z: src K=DM rows, N=FF cols
        src = W1 + (size_t)z * DM * FF;
        dst = W1t + (size_t)z * DM * FF;
        K = DM; N = FF;
        n0 = blockIdx.x * 64; k0 = blockIdx.y * 64;   // x: 48, y: 12
    } else {      // W2 expert z-8: src K=FF rows, N=DM cols
        src = W2 + (size_t)(z - 8) * FF * DM;
        dst = W2t + (size_t)(z - 8) * FF * DM;
        K = FF; N = DM;
        k0 = blockIdx.x * 64; n0 = blockIdx.y * 64;   // x: 48, y: 12
    }
    int tid = threadIdx.x;
    // stage 64k x 64n fp32 -> bf16 LDS [k][n]
#pragma unroll
    for (int j = 0; j < 4; j++) {
        int cid = tid + 256 * j;
        int r = cid >> 4, c4 = cid & 15;
        f32x4_t v = *(const f32x4_t*)&src[(size_t)(k0 + r) * N + n0 + c4 * 4];
        bf16x4_t h;
        h[0] = (short)f2bf(v[0]); h[1] = (short)f2bf(v[1]);
        h[2] = (short)f2bf(v[2]); h[3] = (short)f2bf(v[3]);
        *(bf16x4_t*)&Ls[r * 68 + c4 * 4] = h;
    }
    __syncthreads();
    // write out 64n x 64k bf16, K-contiguous
#pragma unroll
    for (int j = 0; j < 2; j++) {
        int cid = tid + 256 * j;
        int n = cid >> 3, c = cid & 7;
        bf16x8_t o;
#pragma unroll
        for (int kk = 0; kk < 8; kk++) o[kk] = (short)Ls[(c * 8 + kk) * 68 + n];
        *(bf16x8_t*)&dst[(size_t)(n0 + n) * K + k0 + c * 8] = o;
    }
}

// ---- K1: fused LN1 + vproj + x2/LN2 + gate + out-init (8 tokens/block) ----
__global__ __launch_bounds__(256) void k_pre(
        const float* __restrict__ x,
        const float* __restrict__ g1, const float* __restrict__ b1,
        const float* __restrict__ Wv, const float* __restrict__ bv,
        const float* __restrict__ g2, const float* __restrict__ b2g,
        const float* __restrict__ Wg, const float* __restrict__ bg,
        const float* __restrict__ b2moe,
        u16* __restrict__ h2, float* __restrict__ out,
        int* __restrict__ cnt, int* __restrict__ buck) {
    __shared__ __align__(16) u16 h1s[8 * DM];
    __shared__ float wgs[NE * DM];
    __shared__ float g2s[DM], b2s[DM];
    __shared__ float ps[4 * 8 * 64];
    __shared__ float vsm[8 * 64];
    int tid = threadIdx.x, lane = tid & 63, w = tid >> 6;
    int tb = blockIdx.x * 8;

    for (int idx = tid; idx < NE * DM; idx += 256) {
        int e = idx / DM, c = idx % DM;
        wgs[idx] = Wg[(size_t)c * NE + e];
    }
    for (int idx = tid; idx < DM; idx += 256) { g2s[idx] = g2[idx]; b2s[idx] = b2g[idx]; }

    float xv[2][12];
#pragma unroll
    for (int ttl = 0; ttl < 2; ttl++) {
        int tl = w * 2 + ttl;
        int t = tb + tl;
        const float* xp = x + (size_t)t * DM;
        float s = 0.0f;
#pragma unroll
        for (int i = 0; i < 12; i++) { float q = xp[lane + 64 * i]; xv[ttl][i] = q; s += q; }
#pragma unroll
        for (int m = 1; m < 64; m <<= 1) s += __shfl_xor(s, m);
        float mu = s * (1.0f / DM);
        float vs = 0.0f;
#pragma unroll
        for (int i = 0; i < 12; i++) { float d = xv[ttl][i] - mu; vs += d * d; }
#pragma unroll
        for (int m = 1; m < 64; m <<= 1) vs += __shfl_xor(vs, m);
        float rs = rsqrtf(vs * (1.0f / DM) + 1e-5f);
#pragma unroll
        for (int i = 0; i < 12; i++) {
            int c = lane + 64 * i;
            h1s[tl * DM + c] = f2bf((xv[ttl][i] - mu) * rs * g1[c] + b1[c]);
        }
    }
    __syncthreads();

    float acc[8];
#pragma unroll
    for (int tt = 0; tt < 8; tt++) acc[tt] = 0.0f;
    const float* wp = Wv + (size_t)(w * 192) * HD + lane;
    for (int kk = 0; kk < 192; kk += 4) {
        float w0 = wp[(size_t)(kk + 0) * HD];
        float w1 = wp[(size_t)(kk + 1) * HD];
        float w2 = wp[(size_t)(kk + 2) * HD];
        float w3 = wp[(size_t)(kk + 3) * HD];
        int kb = w * 192 + kk;
#pragma unroll
        for (int tt = 0; tt < 8; tt++) {
            bf16x4_t hh = *(const bf16x4_t*)&h1s[tt * DM + kb];
            acc[tt] += bf2f((u16)hh[0]) * w0 + bf2f((u16)hh[1]) * w1 +
                       bf2f((u16)hh[2]) * w2 + bf2f((u16)hh[3]) * w3;
        }
    }
#pragma unroll
    for (int tt = 0; tt < 8; tt++) ps[(w * 8 + tt) * 64 + lane] = acc[tt];
    __syncthreads();
#pragma unroll
    for (int s2 = 0; s2 < 2; s2++) {
        int tt = w * 2 + s2;
        vsm[tt * 64 + lane] = ps[tt * 64 + lane] + ps[(8 + tt) * 64 + lane] +
                              ps[(16 + tt) * 64 + lane] + ps[(24 + tt) * 64 + lane] +
                              bv[lane];
    }
    __syncthreads();

#pragma unroll
    for (int ttl = 0; ttl < 2; ttl++) {
        int tl = w * 2 + ttl;
        int t = tb + tl;
        float vl = vsm[tl * 64 + lane];
        float x2v[12];
        float s = 0.0f;
#pragma unroll
        for (int i = 0; i < 12; i++) { float q = xv[ttl][i] + vl; x2v[i] = q; s += q; }
#pragma unroll
        for (int m = 1; m < 64; m <<= 1) s += __shfl_xor(s, m);
        float mu = s * (1.0f / DM);
        float vs = 0.0f;
#pragma unroll
        for (int i = 0; i < 12; i++) { float d = x2v[i] - mu; vs += d * d; }
#pragma unroll
        for (int m = 1; m < 64; m <<= 1) vs += __shfl_xor(vs, m);
        float rs = rsqrtf(vs * (1.0f / DM) + 1e-5f);
        float le[NE];
#pragma unroll
        for (int e = 0; e < NE; e++) le[e] = 0.0f;
        u16* h2p = h2 + (size_t)t * DM;
#pragma unroll
        for (int i = 0; i < 12; i++) {
            int c = lane + 64 * i;
            float h = (x2v[i] - mu) * rs * g2s[c] + b2s[c];
            h2p[c] = f2bf(h);
#pragma unroll
            for (int e = 0; e < NE; e++) le[e] += h * wgs[e * DM + c];
        }
#pragma unroll
        for (int e = 0; e < NE; e++) {
#pragma unroll
            for (int m = 1; m < 64; m <<= 1) le[e] += __shfl_xor(le[e], m);
        }
        float best = le[0] + bg[0]; int be = 0;
#pragma unroll
        for (int e = 1; e < NE; e++) {
            float q = le[e] + bg[e];
            if (q > best) { best = q; be = e; }   // strict > == first-max (jnp.argmax)
        }
        if (lane == 0) {
            int pos = atomicAdd(&cnt[be], 1);
            buck[be * T_TOK + pos] = t;
        }
        float* op = out + (size_t)t * DM;
        const float* bp = b2moe + (size_t)be * DM;
#pragma unroll
        for (int i = 0; i < 12; i++) {
            int c = lane + 64 * i;
            op[c] = x2v[i] + bp[c];
        }
    }
}

// ---- K2: grouped GEMM1 + gelu: hmid = gelu(h2 @ W1[e] + b1[e]) ----
// BM=128, BN=128, BK=64, NK=12. B = W1t bf16 [ff][dm] (K-contiguous).
__global__ __launch_bounds__(256) void k_moe_gemm1(
        const u16* __restrict__ h2, const u16* __restrict__ W1t,
        const float* __restrict__ b1, const int* __restrict__ cnt,
        const int* __restrict__ buck, u16* __restrict__ hmid) {
    int e = blockIdx.y / MT_MAX, mt = blockIdx.y % MT_MAX;
    int cnte = cnt[e];
    int m0 = mt * 128;
    if (m0 >= cnte) return;                     // uniform drain
    int n0 = blockIdx.x * 128;
    const u16* Bw = W1t + (size_t)e * DM * FF;
    __shared__ __align__(16) u16 As[128 * 72];  // 18 KB
    __shared__ __align__(16) u16 Bs[128 * 72];  // 18 KB
    int tid = threadIdx.x, lane = tid & 63, wid = tid >> 6;
    int srow = tid >> 3, sc = tid & 7;          // staging: rows srow+32j, chunk sc
    int lr = lane & 15, q = lane >> 4;

    int atok[4];
#pragma unroll
    for (int j = 0; j < 4; j++) {
        int i = m0 + srow + 32 * j;
        atok[j] = (i < cnte) ? buck[e * T_TOK + i] : -1;
    }
    f32x4_t acc[2][8];
#pragma unroll
    for (int mi = 0; mi < 2; mi++)
#pragma unroll
        for (int ni = 0; ni < 8; ni++) acc[mi][ni] = (f32x4_t){0.f, 0.f, 0.f, 0.f};

    bf16x8_t a_pre[4], b_pre[4];
#pragma unroll
    for (int j = 0; j < 4; j++) {
        bf16x8_t v = {0, 0, 0, 0, 0, 0, 0, 0};
        if (atok[j] >= 0) v = *(const bf16x8_t*)&h2[(size_t)atok[j] * DM + sc * 8];
        a_pre[j] = v;
        b_pre[j] = *(const bf16x8_t*)&Bw[(size_t)(n0 + srow + 32 * j) * DM + sc * 8];
    }
    const int NK = DM / 64;   // 12
    for (int kt = 0; kt < NK; kt++) {
        __syncthreads();
#pragma unroll
        for (int j = 0; j < 4; j++) {
            *(bf16x8_t*)&As[(srow + 32 * j) * 72 + sc * 8] = a_pre[j];
            *(bf16x8_t*)&Bs[(srow + 32 * j) * 72 + sc * 8] = b_pre[j];
        }
        __syncthreads();
        if (kt + 1 < NK) {
            int k0 = (kt + 1) * 64;
#pragma unroll
            for (int j = 0; j < 4; j++) {
                bf16x8_t v = {0, 0, 0, 0, 0, 0, 0, 0};
                if (atok[j] >= 0)
                    v = *(const bf16x8_t*)&h2[(size_t)atok[j] * DM + k0 + sc * 8];
                a_pre[j] = v;
                b_pre[j] = *(const bf16x8_t*)&Bw[(size_t)(n0 + srow + 32 * j) * DM + k0 + sc * 8];
            }
        }
#pragma unroll
        for (int s = 0; s < 2; s++) {
            bf16x8_t af[2];
#pragma unroll
            for (int mi = 0; mi < 2; mi++)
                af[mi] = *(const bf16x8_t*)&As[(wid * 32 + mi * 16 + lr) * 72 + s * 32 + q * 8];
#pragma unroll
            for (int ni = 0; ni < 8; ni++) {
                bf16x8_t bfr = *(const bf16x8_t*)&Bs[(ni * 16 + lr) * 72 + s * 32 + q * 8];
#pragma unroll
                for (int mi = 0; mi < 2; mi++)
                    acc[mi][ni] = __builtin_amdgcn_mfma_f32_16x16x32_bf16(af[mi], bfr, acc[mi][ni], 0, 0, 0);
            }
        }
    }
    float bias[8];
#pragma unroll
    for (int ni = 0; ni < 8; ni++) bias[ni] = b1[(size_t)e * FF + n0 + ni * 16 + lr];
#pragma unroll
    for (int mi = 0; mi < 2; mi++) {
#pragma unroll
        for (int r = 0; r < 4; r++) {
            int i = m0 + wid * 32 + mi * 16 + q * 4 + r;
            if (i < cnte) {
                int t = buck[e * T_TOK + i];
                size_t base = (size_t)t * FF + n0;
#pragma unroll
                for (int ni = 0; ni < 8; ni++)
                    hmid[base + ni * 16 + lr] = f2bf(gelu_f(acc[mi][ni][r] + bias[ni]));
            }
        }
    }
}

// ---- K3: grouped GEMM2, split-K x4, partials (no atomics) ----
// BM=128, BN=128, BK=64, K-chunk=768, NK=12. B = W2t bf16 [dm][ff].
__global__ __launch_bounds__(256) void k_moe_gemm2(
        const u16* __restrict__ hmid, const u16* __restrict__ W2t,
        const int* __restrict__ cnt, const int* __restrict__ buck,
        float* __restrict__ part) {
    int y = blockIdx.y;                 // 0..415: e(8) x mt(13) x kc(4)
    int e = y / (MT_MAX * 4);
    int rem = y % (MT_MAX * 4);
    int mt = rem >> 2, kc = rem & 3;
    int cnte = cnt[e];
    int m0 = mt * 128;
    if (m0 >= cnte) return;
    int n0 = blockIdx.x * 128;
    int kbase = kc * (FF / 4);
    int off = 0;
    for (int ee = 0; ee < NE; ee++) off += (ee < e) ? cnt[ee] : 0;
    const u16* Bw = W2t + (size_t)e * DM * FF;
    __shared__ __align__(16) u16 As[128 * 72];
    __shared__ __align__(16) u16 Bs[128 * 72];
    int tid = threadIdx.x, lane = tid & 63, wid = tid >> 6;
    int srow = tid >> 3, sc = tid & 7;
    int lr = lane & 15, q = lane >> 4;

    int atok[4];
#pragma unroll
    for (int j = 0; j < 4; j++) {
        int i = m0 + srow + 32 * j;
        atok[j] = (i < cnte) ? buck[e * T_TOK + i] : -1;
    }
    f32x4_t acc[2][8];
#pragma unroll
    for (int mi = 0; mi < 2; mi++)
#pragma unroll
        for (int ni = 0; ni < 8; ni++) acc[mi][ni] = (f32x4_t){0.f, 0.f, 0.f, 0.f};

    bf16x8_t a_pre[4], b_pre[4];
#pragma unroll
    for (int j = 0; j < 4; j++) {
        bf16x8_t v = {0, 0, 0, 0, 0, 0, 0, 0};
        if (atok[j] >= 0)
            v = *(const bf16x8_t*)&hmid[(size_t)atok[j] * FF + kbase + sc * 8];
        a_pre[j] = v;
        b_pre[j] = *(const bf16x8_t*)&Bw[(size_t)(n0 + srow + 32 * j) * FF + kbase + sc * 8];
    }
    const int NK = (FF / 4) / 64;   // 12
    for (int kt = 0; kt < NK; kt++) {
        __syncthreads();
#pragma unroll
        for (int j = 0; j < 4; j++) {
            *(bf16x8_t*)&As[(srow + 32 * j) * 72 + sc * 8] = a_pre[j];
            *(bf16x8_t*)&Bs[(srow + 32 * j) * 72 + sc * 8] = b_pre[j];
        }
        __syncthreads();
        if (kt + 1 < NK) {
            int k0 = kbase + (kt + 1) * 64;
#pragma unroll
            for (int j = 0; j < 4; j++) {
                bf16x8_t v = {0, 0, 0, 0, 0, 0, 0, 0};
                if (atok[j] >= 0)
                    v = *(const bf16x8_t*)&hmid[(size_t)atok[j] * FF + k0 + sc * 8];
                a_pre[j] = v;
                b_pre[j] = *(const bf16x8_t*)&Bw[(size_t)(n0 + srow + 32 * j) * FF + k0 + sc * 8];
            }
        }
#pragma unroll
        for (int s = 0; s < 2; s++) {
            bf16x8_t af[2];
#pragma unroll
            for (int mi = 0; mi < 2; mi++)
                af[mi] = *(const bf16x8_t*)&As[(wid * 32 + mi * 16 + lr) * 72 + s * 32 + q * 8];
#pragma unroll
            for (int ni = 0; ni < 8; ni++) {
                bf16x8_t bfr = *(const bf16x8_t*)&Bs[(ni * 16 + lr) * 72 + s * 32 + q * 8];
#pragma unroll
                for (int mi = 0; mi < 2; mi++)
                    acc[mi][ni] = __builtin_amdgcn_mfma_f32_16x16x32_bf16(af[mi], bfr, acc[mi][ni], 0, 0, 0);
            }
        }
    }
    // partial store at compact row g = off + i (no atomics)
    float* pbase = part + (size_t)kc * T_TOK * DM;
#pragma unroll
    for (int mi = 0; mi < 2; mi++) {
#pragma unroll
        for (int r = 0; r < 4; r++) {
            int i = m0 + wid * 32 + mi * 16 + q * 4 + r;
            if (i < cnte) {
                float* pp = pbase + (size_t)(off + i) * DM + n0;
#pragma unroll
                for (int ni = 0; ni < 8; ni++)
                    pp[ni * 16 + lr] = acc[mi][ni][r];
            }
        }
    }
}

// ---- K4: out[t] += sum_kc part[kc][g]  (each (t,c) touched exactly once) ----
__global__ __launch_bounds__(256) void k_reduce(
        const float* __restrict__ part, const int* __restrict__ cnt,
        const int* __restrict__ buck, float* __restrict__ out) {
    int y = blockIdx.y;                 // 0..103: e(8) x mt(13)
    int e = y / MT_MAX, mt = y % MT_MAX;
    int cnte = cnt[e];
    int m0 = mt * 128;
    if (m0 >= cnte) return;
    int off = 0;
    for (int ee = 0; ee < NE; ee++) off += (ee < e) ? cnt[ee] : 0;
    int n0 = blockIdx.x * 128;
    int tid = threadIdx.x;
    int rl = tid >> 1, half = tid & 1;
    int i = m0 + rl;
    if (i >= cnte) return;
    int t = buck[e * T_TOK + i];
    int g = off + i;
    size_t colb = (size_t)n0 + half * 64;
    const float* p0 = part + (size_t)0 * T_TOK * DM + (size_t)g * DM + colb;
    const float* p1 = part + (size_t)1 * T_TOK * DM + (size_t)g * DM + colb;
    const float* p2 = part + (size_t)2 * T_TOK * DM + (size_t)g * DM + colb;
    const float* p3 = part + (size_t)3 * T_TOK * DM + (size_t)g * DM + colb;
    float* op = out + (size_t)t * DM + colb;
#pragma unroll
    for (int v = 0; v < 16; v++) {
        f32x4_t s = *(const f32x4_t*)&p0[v * 4];
        s += *(const f32x4_t*)&p1[v * 4];
        s += *(const f32x4_t*)&p2[v * 4];
        s += *(const f32x4_t*)&p3[v * 4];
        f32x4_t o = *(const f32x4_t*)&op[v * 4];
        *(f32x4_t*)&op[v * 4] = o + s;
    }
}

extern "C" void kernel_launch(void* const* d_in, const int* in_sizes, int n_in,
                              void* d_out, int out_size, void* d_ws, size_t ws_size,
                              hipStream_t stream) {
    const float* x    = (const float*)d_in[0];
    const float* ln1g = (const float*)d_in[1];
    const float* ln1b = (const float*)d_in[2];
    // d_in[3..6] = Wq,bq,Wk,bk: dead code
    const float* Wv   = (const float*)d_in[7];
    const float* bv   = (const float*)d_in[8];
    const float* ln2g = (const float*)d_in[9];
    const float* ln2b = (const float*)d_in[10];
    const float* Wg   = (const float*)d_in[11];
    const float* bg   = (const float*)d_in[12];
    const float* W1   = (const float*)d_in[13];
    const float* b1   = (const float*)d_in[14];
    const float* W2   = (const float*)d_in[15];
    const float* b2   = (const float*)d_in[16];

    char* ws = (char*)d_ws;
    int*   cnt  = (int*)(ws + OFF_CNT);
    int*   buck = (int*)(ws + OFF_BUCK);
    u16*   h2   = (u16*)(ws + OFF_H2);
    u16*   hmid = (u16*)(ws + OFF_HMID);
    u16*   W1t  = (u16*)(ws + OFF_W1T);
    u16*   W2t  = (u16*)(ws + OFF_W2T);
    float* part = (float*)(ws + OFF_PART);
    float* out  = (float*)d_out;

    hipMemsetAsync(cnt, 0, 16 * sizeof(int), stream);
    k_wt<<<dim3(48, 12, 16), 256, 0, stream>>>(W1, W2, W1t, W2t);
    k_pre<<<T_TOK / 8, 256, 0, stream>>>(x, ln1g, ln1b, Wv, bv, ln2g, ln2b,
                                         Wg, bg, b2, h2, out, cnt, buck);
    k_moe_gemm1<<<dim3(FF / 128, NE * MT_MAX), 256, 0, stream>>>(
        h2, W1t, b1, cnt, buck, hmid);
    k_moe_gemm2<<<dim3(DM / 128, NE * MT_MAX * 4), 256, 0, stream>>>(
        hmid, W2t, cnt, buck, part);
    k_reduce<<<dim3(DM / 128, NE * MT_MAX), 256, 0, stream>>>(part, cnt, buck, out);
}

// Round 6
// 317.280 us; speedup vs baseline: 1.0965x; 1.0965x over previous
//
#include <hip/hip_runtime.h>

// TransformerBlock: B=8,S=196,D=768,H=12,HD=64,E=8,FF=3072. T = B*S = 1568 tokens.
//
// Exact simplifications:
//  - attention: k,v broadcast across heads -> softmax uniform -> attn_out = tile(v).
//    Wq/bq/Wk/bk/RoPE are dead code.
//  - MoE top-1 = argmax of gating logits (softmax monotone).
//
// R5:
//  - No weight transpose pass. GEMMs read W fp32 directly (coalesced f32x4 ->
//    LDS fp32), per-fragment strided ds_read_b32 + cvt to bf16.
//  - K-loop barriers are hand-rolled `s_waitcnt lgkmcnt(0); s_barrier` (LDS-only
//    drain) so depth-2 global prefetch stays in flight across barriers
//    (__syncthreads drains vmcnt(0) every iter = the R1-R4 ~60us GEMM plateau).
//  - gemm2 split-K x4 -> fp32 partials -> k_reduce (no atomics).

typedef unsigned short u16;
typedef short bf16x8_t __attribute__((ext_vector_type(8)));
typedef short bf16x4_t __attribute__((ext_vector_type(4)));
typedef float f32x4_t  __attribute__((ext_vector_type(4)));

#define T_TOK 1568
#define DM 768
#define HD 64
#define FF 3072
#define NE 8
#define MT_MAX 13          // m-tiles per expert upper bound at BM=128

// workspace layout, ~31.4 MB
#define OFF_CNT   0
#define OFF_BUCK  64
#define OFF_H2    50304
#define OFF_HMID  2458752
#define OFF_PART  12092544

__device__ __forceinline__ float bf2f(u16 h) {
    unsigned u = ((unsigned)h) << 16;
    return __builtin_bit_cast(float, u);
}
__device__ __forceinline__ u16 f2bf(float f) {  // round-to-nearest-even
    unsigned u = __builtin_bit_cast(unsigned, f);
    unsigned r = (u + 0x7FFFu + ((u >> 16) & 1u)) >> 16;
    return (u16)r;
}
__device__ __forceinline__ float gelu_f(float x) {
    return 0.5f * x * (1.0f + erff(x * 0.70710678118654752440f));
}
// LDS-only barrier: does NOT drain outstanding global loads (vmcnt untouched).
__device__ __forceinline__ void bar_lds() {
    asm volatile("s_waitcnt lgkmcnt(0)\n\ts_barrier" ::: "memory");
}

// ---- K1: fused LN1 + vproj + x2/LN2 + gate + out-init (8 tokens/block) ----
__global__ __launch_bounds__(256) void k_pre(
        const float* __restrict__ x,
        const float* __restrict__ g1, const float* __restrict__ b1,
        const float* __restrict__ Wv, const float* __restrict__ bv,
        const float* __restrict__ g2, const float* __restrict__ b2g,
        const float* __restrict__ Wg, const float* __restrict__ bg,
        const float* __restrict__ b2moe,
        u16* __restrict__ h2, float* __restrict__ out,
        int* __restrict__ cnt, int* __restrict__ buck) {
    __shared__ __align__(16) u16 h1s[8 * DM];
    __shared__ float wgs[NE * DM];
    __shared__ float g2s[DM], b2s[DM];
    __shared__ float ps[4 * 8 * 64];
    __shared__ float vsm[8 * 64];
    int tid = threadIdx.x, lane = tid & 63, w = tid >> 6;
    int tb = blockIdx.x * 8;

    for (int idx = tid; idx < NE * DM; idx += 256) {
        int e = idx / DM, c = idx % DM;
        wgs[idx] = Wg[(size_t)c * NE + e];
    }
    for (int idx = tid; idx < DM; idx += 256) { g2s[idx] = g2[idx]; b2s[idx] = b2g[idx]; }

    float xv[2][12];
#pragma unroll
    for (int ttl = 0; ttl < 2; ttl++) {
        int tl = w * 2 + ttl;
        int t = tb + tl;
        const float* xp = x + (size_t)t * DM;
        float s = 0.0f;
#pragma unroll
        for (int i = 0; i < 12; i++) { float q = xp[lane + 64 * i]; xv[ttl][i] = q; s += q; }
#pragma unroll
        for (int m = 1; m < 64; m <<= 1) s += __shfl_xor(s, m);
        float mu = s * (1.0f / DM);
        float vs = 0.0f;
#pragma unroll
        for (int i = 0; i < 12; i++) { float d = xv[ttl][i] - mu; vs += d * d; }
#pragma unroll
        for (int m = 1; m < 64; m <<= 1) vs += __shfl_xor(vs, m);
        float rs = rsqrtf(vs * (1.0f / DM) + 1e-5f);
#pragma unroll
        for (int i = 0; i < 12; i++) {
            int c = lane + 64 * i;
            h1s[tl * DM + c] = f2bf((xv[ttl][i] - mu) * rs * g1[c] + b1[c]);
        }
    }
    __syncthreads();

    float acc[8];
#pragma unroll
    for (int tt = 0; tt < 8; tt++) acc[tt] = 0.0f;
    const float* wp = Wv + (size_t)(w * 192) * HD + lane;
    for (int kk = 0; kk < 192; kk += 4) {
        float w0 = wp[(size_t)(kk + 0) * HD];
        float w1 = wp[(size_t)(kk + 1) * HD];
        float w2 = wp[(size_t)(kk + 2) * HD];
        float w3 = wp[(size_t)(kk + 3) * HD];
        int kb = w * 192 + kk;
#pragma unroll
        for (int tt = 0; tt < 8; tt++) {
            bf16x4_t hh = *(const bf16x4_t*)&h1s[tt * DM + kb];
            acc[tt] += bf2f((u16)hh[0]) * w0 + bf2f((u16)hh[1]) * w1 +
                       bf2f((u16)hh[2]) * w2 + bf2f((u16)hh[3]) * w3;
        }
    }
#pragma unroll
    for (int tt = 0; tt < 8; tt++) ps[(w * 8 + tt) * 64 + lane] = acc[tt];
    __syncthreads();
#pragma unroll
    for (int s2 = 0; s2 < 2; s2++) {
        int tt = w * 2 + s2;
        vsm[tt * 64 + lane] = ps[tt * 64 + lane] + ps[(8 + tt) * 64 + lane] +
                              ps[(16 + tt) * 64 + lane] + ps[(24 + tt) * 64 + lane] +
                              bv[lane];
    }
    __syncthreads();

#pragma unroll
    for (int ttl = 0; ttl < 2; ttl++) {
        int tl = w * 2 + ttl;
        int t = tb + tl;
        float vl = vsm[tl * 64 + lane];
        float x2v[12];
        float s = 0.0f;
#pragma unroll
        for (int i = 0; i < 12; i++) { float q = xv[ttl][i] + vl; x2v[i] = q; s += q; }
#pragma unroll
        for (int m = 1; m < 64; m <<= 1) s += __shfl_xor(s, m);
        float mu = s * (1.0f / DM);
        float vs = 0.0f;
#pragma unroll
        for (int i = 0; i < 12; i++) { float d = x2v[i] - mu; vs += d * d; }
#pragma unroll
        for (int m = 1; m < 64; m <<= 1) vs += __shfl_xor(vs, m);
        float rs = rsqrtf(vs * (1.0f / DM) + 1e-5f);
        float le[NE];
#pragma unroll
        for (int e = 0; e < NE; e++) le[e] = 0.0f;
        u16* h2p = h2 + (size_t)t * DM;
#pragma unroll
        for (int i = 0; i < 12; i++) {
            int c = lane + 64 * i;
            float h = (x2v[i] - mu) * rs * g2s[c] + b2s[c];
            h2p[c] = f2bf(h);
#pragma unroll
            for (int e = 0; e < NE; e++) le[e] += h * wgs[e * DM + c];
        }
#pragma unroll
        for (int e = 0; e < NE; e++) {
#pragma unroll
            for (int m = 1; m < 64; m <<= 1) le[e] += __shfl_xor(le[e], m);
        }
        float best = le[0] + bg[0]; int be = 0;
#pragma unroll
        for (int e = 1; e < NE; e++) {
            float q = le[e] + bg[e];
            if (q > best) { best = q; be = e; }   // strict > == first-max (jnp.argmax)
        }
        if (lane == 0) {
            int pos = atomicAdd(&cnt[be], 1);
            buck[be * T_TOK + pos] = t;
        }
        float* op = out + (size_t)t * DM;
        const float* bp = b2moe + (size_t)be * DM;
#pragma unroll
        for (int i = 0; i < 12; i++) {
            int c = lane + 64 * i;
            op[c] = x2v[i] + bp[c];
        }
    }
}

// ================= GEMM core macros (BM=128, BN=128, BK=32) =================
// A bf16 gathered rows -> LDS [row][40]; B fp32 [k][n] coalesced -> LDS [k][133].
// 2x2 wave grid: wave (wm,wn) covers rows wm*64..+63, cols wn*64..+63.
// Per-iter: LDS-only barrier, stage, barrier, prefetch k+2, frags+MFMA.

#define GEMM_DECLS()                                                          \
    int tid = threadIdx.x, lane = tid & 63, wid = tid >> 6;                   \
    int wm = wid >> 1, wn = wid & 1, lr = lane & 15, q = lane >> 4;           \
    int ar = tid >> 2, ac4 = tid & 3;  /* A rows ar, ar+64; 16B chunk ac4 */  \
    int nc = tid & 31, kr = tid >> 5;  /* B n-chunk nc*4, k rows kr+8p   */   \
    __shared__ __align__(16) u16 As[128 * 40];                                \
    __shared__ __align__(16) float Lf[32 * 133];

#define GEMM_FRAG_MFMA()                                                      \
    {                                                                         \
        bf16x8_t af[4];                                                       \
        _Pragma("unroll")                                                     \
        for (int mi = 0; mi < 4; mi++)                                        \
            af[mi] = *(const bf16x8_t*)&As[(wm * 64 + mi * 16 + lr) * 40 + q * 8]; \
        _Pragma("unroll")                                                     \
        for (int ni = 0; ni < 4; ni++) {                                      \
            const float* lp = &Lf[q * 8 * 133 + wn * 64 + ni * 16 + lr];      \
            bf16x8_t bb;                                                      \
            _Pragma("unroll")                                                 \
            for (int j = 0; j < 8; j++) bb[j] = (short)f2bf(lp[j * 133]);     \
            _Pragma("unroll")                                                 \
            for (int mi = 0; mi < 4; mi++)                                    \
                acc[mi][ni] = __builtin_amdgcn_mfma_f32_16x16x32_bf16(        \
                    af[mi], bb, acc[mi][ni], 0, 0, 0);                        \
        }                                                                     \
    }

#define GEMM_STAGE(pa, pb)                                                    \
    *(bf16x8_t*)&As[ar * 40 + ac4 * 8] = pa[0];                               \
    *(bf16x8_t*)&As[(ar + 64) * 40 + ac4 * 8] = pa[1];                        \
    _Pragma("unroll")                                                         \
    for (int p = 0; p < 4; p++)                                               \
        *(f32x4_t*)&Lf[(kr + 8 * p) * 133 + nc * 4] = pb[p];

// ---- K2: grouped GEMM1 + gelu: hmid = gelu(h2 @ W1[e] + b1[e]) ----
__global__ __launch_bounds__(256) void k_moe_gemm1(
        const u16* __restrict__ h2, const float* __restrict__ W1,
        const float* __restrict__ b1, const int* __restrict__ cnt,
        const int* __restrict__ buck, u16* __restrict__ hmid) {
    int e = blockIdx.y / MT_MAX, mt = blockIdx.y % MT_MAX;
    int cnte = cnt[e];
    int m0 = mt * 128;
    if (m0 >= cnte) return;
    int n0 = blockIdx.x * 128;
    const float* Bg = W1 + (size_t)e * DM * FF;
    GEMM_DECLS();

    int atok0, atok1;
    { int i0 = m0 + ar, i1 = m0 + ar + 64;
      atok0 = (i0 < cnte) ? buck[e * T_TOK + i0] : -1;
      atok1 = (i1 < cnte) ? buck[e * T_TOK + i1] : -1; }

    f32x4_t acc[4][4];
#pragma unroll
    for (int mi = 0; mi < 4; mi++)
#pragma unroll
        for (int ni = 0; ni < 4; ni++) acc[mi][ni] = (f32x4_t){0.f, 0.f, 0.f, 0.f};

    bf16x8_t pA0[2], pA1[2];
    f32x4_t pB0[4], pB1[4];
#define G1_LOAD(pa, pb, kk)                                                   \
    {                                                                         \
        bf16x8_t z = {0,0,0,0,0,0,0,0};                                       \
        pa[0] = (atok0 >= 0) ? *(const bf16x8_t*)&h2[(size_t)atok0 * DM + (kk) + ac4 * 8] : z; \
        pa[1] = (atok1 >= 0) ? *(const bf16x8_t*)&h2[(size_t)atok1 * DM + (kk) + ac4 * 8] : z; \
        _Pragma("unroll")                                                     \
        for (int p = 0; p < 4; p++)                                           \
            pb[p] = *(const f32x4_t*)&Bg[(size_t)((kk) + kr + 8 * p) * FF + n0 + nc * 4]; \
    }
    G1_LOAD(pA0, pB0, 0);
    G1_LOAD(pA1, pB1, 32);
    const int NK = DM / 32;   // 24
#pragma unroll 1
    for (int kt2 = 0; kt2 < NK / 2; kt2++) {
        int k = kt2 * 2 * 32;
        bar_lds();
        GEMM_STAGE(pA0, pB0);
        bar_lds();
        if (k + 64 < NK * 32) G1_LOAD(pA0, pB0, k + 64);
        GEMM_FRAG_MFMA();
        bar_lds();
        GEMM_STAGE(pA1, pB1);
        bar_lds();
        if (k + 96 < NK * 32) G1_LOAD(pA1, pB1, k + 96);
        GEMM_FRAG_MFMA();
    }
#undef G1_LOAD
    // epilogue: bias + gelu, scatter by token id
#pragma unroll
    for (int mi = 0; mi < 4; mi++) {
#pragma unroll
        for (int r = 0; r < 4; r++) {
            int i = m0 + wm * 64 + mi * 16 + q * 4 + r;
            if (i < cnte) {
                int t = buck[e * T_TOK + i];
                size_t base = (size_t)t * FF + n0 + wn * 64;
#pragma unroll
                for (int ni = 0; ni < 4; ni++) {
                    float bias = b1[(size_t)e * FF + n0 + wn * 64 + ni * 16 + lr];
                    hmid[base + ni * 16 + lr] = f2bf(gelu_f(acc[mi][ni][r] + bias));
                }
            }
        }
    }
}

// ---- K3: grouped GEMM2, split-K x4, fp32 partials (no atomics) ----
__global__ __launch_bounds__(256) void k_moe_gemm2(
        const u16* __restrict__ hmid, const float* __restrict__ W2,
        const int* __restrict__ cnt, const int* __restrict__ buck,
        float* __restrict__ part) {
    int y = blockIdx.y;                 // e(8) x mt(13) x kc(4)
    int e = y / (MT_MAX * 4);
    int rem = y % (MT_MAX * 4);
    int mt = rem >> 2, kc = rem & 3;
    int cnte = cnt[e];
    int m0 = mt * 128;
    if (m0 >= cnte) return;
    int n0 = blockIdx.x * 128;
    int kbase = kc * (FF / 4);
    int off = 0;
    for (int ee = 0; ee < NE; ee++) off += (ee < e) ? cnt[ee] : 0;
    const float* Bg = W2 + (size_t)e * FF * DM;
    GEMM_DECLS();

    int atok0, atok1;
    { int i0 = m0 + ar, i1 = m0 + ar + 64;
      atok0 = (i0 < cnte) ? buck[e * T_TOK + i0] : -1;
      atok1 = (i1 < cnte) ? buck[e * T_TOK + i1] : -1; }

    f32x4_t acc[4][4];
#pragma unroll
    for (int mi = 0; mi < 4; mi++)
#pragma unroll
        for (int ni = 0; ni < 4; ni++) acc[mi][ni] = (f32x4_t){0.f, 0.f, 0.f, 0.f};

    bf16x8_t pA0[2], pA1[2];
    f32x4_t pB0[4], pB1[4];
#define G2_LOAD(pa, pb, kk)                                                   \
    {                                                                         \
        bf16x8_t z = {0,0,0,0,0,0,0,0};                                       \
        pa[0] = (atok0 >= 0) ? *(const bf16x8_t*)&hmid[(size_t)atok0 * FF + kbase + (kk) + ac4 * 8] : z; \
        pa[1] = (atok1 >= 0) ? *(const bf16x8_t*)&hmid[(size_t)atok1 * FF + kbase + (kk) + ac4 * 8] : z; \
        _Pragma("unroll")                                                     \
        for (int p = 0; p < 4; p++)                                           \
            pb[p] = *(const f32x4_t*)&Bg[(size_t)(kbase + (kk) + kr + 8 * p) * DM + n0 + nc * 4]; \
    }
    G2_LOAD(pA0, pB0, 0);
    G2_LOAD(pA1, pB1, 32);
    const int NK = (FF / 4) / 32;   // 24
#pragma unroll 1
    for (int kt2 = 0; kt2 < NK / 2; kt2++) {
        int k = kt2 * 2 * 32;
        bar_lds();
        GEMM_STAGE(pA0, pB0);
        bar_lds();
        if (k + 64 < NK * 32) G2_LOAD(pA0, pB0, k + 64);
        GEMM_FRAG_MFMA();
        bar_lds();
        GEMM_STAGE(pA1, pB1);
        bar_lds();
        if (k + 96 < NK * 32) G2_LOAD(pA1, pB1, k + 96);
        GEMM_FRAG_MFMA();
    }
#undef G2_LOAD
    // partial store at compact row g = off + i
    float* pbase = part + (size_t)kc * T_TOK * DM;
#pragma unroll
    for (int mi = 0; mi < 4; mi++) {
#pragma unroll
        for (int r = 0; r < 4; r++) {
            int i = m0 + wm * 64 + mi * 16 + q * 4 + r;
            if (i < cnte) {
                float* pp = pbase + (size_t)(off + i) * DM + n0 + wn * 64;
#pragma unroll
                for (int ni = 0; ni < 4; ni++)
                    pp[ni * 16 + lr] = acc[mi][ni][r];
            }
        }
    }
}

// ---- K4: out[t] += sum_kc part[kc][g] ----
__global__ __launch_bounds__(256) void k_reduce(
        const float* __restrict__ part, const int* __restrict__ cnt,
        const int* __restrict__ buck, float* __restrict__ out) {
    int y = blockIdx.y;                 // e(8) x mt(13)
    int e = y / MT_MAX, mt = y % MT_MAX;
    int cnte = cnt[e];
    int m0 = mt * 128;
    if (m0 >= cnte) return;
    int off = 0;
    for (int ee = 0; ee < NE; ee++) off += (ee < e) ? cnt[ee] : 0;
    int n0 = blockIdx.x * 128;
    int tid = threadIdx.x;
    int rl = tid >> 1, half = tid & 1;
    int i = m0 + rl;
    if (i >= cnte) return;
    int t = buck[e * T_TOK + i];
    int g = off + i;
    size_t colb = (size_t)n0 + half * 64;
    const float* p0 = part + (size_t)0 * T_TOK * DM + (size_t)g * DM + colb;
    const float* p1 = part + (size_t)1 * T_TOK * DM + (size_t)g * DM + colb;
    const float* p2 = part + (size_t)2 * T_TOK * DM + (size_t)g * DM + colb;
    const float* p3 = part + (size_t)3 * T_TOK * DM + (size_t)g * DM + colb;
    float* op = out + (size_t)t * DM + colb;
#pragma unroll
    for (int v = 0; v < 16; v++) {
        f32x4_t s = *(const f32x4_t*)&p0[v * 4];
        s += *(const f32x4_t*)&p1[v * 4];
        s += *(const f32x4_t*)&p2[v * 4];
        s += *(const f32x4_t*)&p3[v * 4];
        f32x4_t o = *(const f32x4_t*)&op[v * 4];
        *(f32x4_t*)&op[v * 4] = o + s;
    }
}

extern "C" void kernel_launch(void* const* d_in, const int* in_sizes, int n_in,
                              void* d_out, int out_size, void* d_ws, size_t ws_size,
                              hipStream_t stream) {
    const float* x    = (const float*)d_in[0];
    const float* ln1g = (const float*)d_in[1];
    const float* ln1b = (const float*)d_in[2];
    // d_in[3..6] = Wq,bq,Wk,bk: dead code
    const float* Wv   = (const float*)d_in[7];
    const float* bv   = (const float*)d_in[8];
    const float* ln2g = (const float*)d_in[9];
    const float* ln2b = (const float*)d_in[10];
    const float* Wg   = (const float*)d_in[11];
    const float* bg   = (const float*)d_in[12];
    const float* W1   = (const float*)d_in[13];
    const float* b1   = (const float*)d_in[14];
    const float* W2   = (const float*)d_in[15];
    const float* b2   = (const float*)d_in[16];

    char* ws = (char*)d_ws;
    int*   cnt  = (int*)(ws + OFF_CNT);
    int*   buck = (int*)(ws + OFF_BUCK);
    u16*   h2   = (u16*)(ws + OFF_H2);
    u16*   hmid = (u16*)(ws + OFF_HMID);
    float* part = (float*)(ws + OFF_PART);
    float* out  = (float*)d_out;

    hipMemsetAsync(cnt, 0, 16 * sizeof(int), stream);
    k_pre<<<T_TOK / 8, 256, 0, stream>>>(x, ln1g, ln1b, Wv, bv, ln2g, ln2b,
                                         Wg, bg, b2, h2, out, cnt, buck);
    k_moe_gemm1<<<dim3(FF / 128, NE * MT_MAX), 256, 0, stream>>>(
        h2, W1, b1, cnt, buck, hmid);
    k_moe_gemm2<<<dim3(DM / 128, NE * MT_MAX * 4), 256, 0, stream>>>(
        hmid, W2, cnt, buck, part);
    k_reduce<<<dim3(DM / 128, NE * MT_MAX), 256, 0, stream>>>(part, cnt, buck, out);
}